// Round 12
// baseline (503.504 us; speedup 1.0000x reference)
//
#include <hip/hip_runtime.h>
#include <hip/hip_bf16.h>
#include <math.h>

#define T_LEN 65536
#define B_N   8
#define BT    (T_LEN * B_N)
#define L_N   16
#define RC    32
#define SC    64

// pass1: per-layer dispatches. 256 thr x 2 elems = 512 outputs/block.
#define NT1   256
#define CL    512

// pass2 tiling
#define TS    128

// folded-weight array offsets (per layer, 14 arrays of 32)
#define A_AF0 0
#define A_AF1 32
#define A_AF2 64
#define A_CF0 96
#define A_CF1 128
#define A_BFC 160
#define A_AG0 192
#define A_AG1 224
#define A_AG2 256
#define A_CG0 288
#define A_CG1 320
#define A_BGC 352
#define A_BFI 384            // bfc+cf0+cf1 (interior: masks statically 1)
#define A_BGI 416            // bgc+cg0+cg1
#define FW_L  448
#define FW_BSUM (L_N * FW_L)     // 7168, +64
#define FW_F32  (FW_BSUM + 64)   // float count; bf16 tables follow as shorts
#define WSBF_N  (L_N * SC * RC)   // 32768 shorts
#define W1BF_N  (SC * SC)         // 4096 shorts

typedef float v2f __attribute__((ext_vector_type(2)));
typedef __attribute__((ext_vector_type(4))) float f4;
typedef __attribute__((ext_vector_type(8))) short bf8;

#define MFMA16(a, b, c) __builtin_amdgcn_mfma_f32_16x16x32_bf16(a, b, c, 0, 0, 0)

__device__ __forceinline__ float fast_rcp(float x) { return __builtin_amdgcn_rcpf(x); }

// fp,gp arrive pre-scaled by 2*log2(e) / log2(e) (folded in prep), so the
// hardware 2^x op is used directly: E = e^{2f}, F = e^{g}.
__device__ __forceinline__ float gated_fn(float fp, float gp) {
    float E = __builtin_amdgcn_exp2f(fp);
    float F = __builtin_amdgcn_exp2f(gp);
    return (E - 1.f) * F * fast_rcp((E + 1.f) * (F + 1.f));
}

// f32 -> bf16 round-to-nearest-even (values finite; no NaN handling needed)
__device__ __forceinline__ unsigned short f2bf(float f) {
    unsigned u = __float_as_uint(f);
    u += 0x7fffu + ((u >> 16) & 1u);
    return (unsigned short)(u >> 16);
}

__device__ __forceinline__ unsigned pk2(float lo, float hi) {
    __hip_bfloat162 h = __float22bfloat162_rn(make_float2(lo, hi));
    unsigned u; __builtin_memcpy(&u, &h, 4); return u;
}

__device__ __forceinline__ bf8 mk_bf8(unsigned a, unsigned b, unsigned c, unsigned d) {
    unsigned v[4] = {a, b, c, d};
    bf8 r; __builtin_memcpy(&r, v, 16); return r;
}

// ---------------------------------------------------------------------------
// prep: fold gate weights (pre-scaled for exp2); Bsum; bf16 W_s / W_sk1.
// ---------------------------------------------------------------------------
__global__ __launch_bounds__(256) void prep_kernel(
    const float* __restrict__ W_f, const float* __restrict__ W_g,
    const float* __restrict__ W_in, const float* __restrict__ b_in,
    const float* __restrict__ b_f, const float* __restrict__ b_g,
    const float* __restrict__ b_s, const float* __restrict__ W_s,
    const float* __restrict__ W_sk1, float* __restrict__ fw,
    short* __restrict__ fwh)
{
    const float SF = 2.88539008177792681472f;  // 2*log2(e)
    const float SG = 1.44269504088896340736f;  // log2(e)
    int idx = blockIdx.x * 256 + threadIdx.x;
    if (idx < L_N * RC) {
        int i = idx >> 5, c = idx & 31;
        float af[3] = {0,0,0}, cf[3] = {0,0,0}, ag[3] = {0,0,0}, cg[3] = {0,0,0};
        for (int cin = 0; cin < RC; ++cin) {
            float wi = W_in[i * RC + cin];
            float bi = b_in[i * RC + cin];
            #pragma unroll
            for (int k = 0; k < 3; ++k) {
                float wf = W_f[((i * RC + c) * RC + cin) * 3 + k];
                float wg = W_g[((i * RC + c) * RC + cin) * 3 + k];
                af[k] = fmaf(wf, wi, af[k]);
                cf[k] = fmaf(wf, bi, cf[k]);
                ag[k] = fmaf(wg, wi, ag[k]);
                cg[k] = fmaf(wg, bi, cg[k]);
            }
        }
        float* p = fw + i * FW_L;
        p[A_AF0 + c] = af[0] * SF; p[A_AF1 + c] = af[1] * SF; p[A_AF2 + c] = af[2] * SF;
        p[A_CF0 + c] = cf[0] * SF; p[A_CF1 + c] = cf[1] * SF;
        p[A_BFC + c] = (b_f[i * RC + c] + cf[2]) * SF;
        p[A_BFI + c] = (b_f[i * RC + c] + cf[2] + cf[0] + cf[1]) * SF;
        p[A_AG0 + c] = ag[0] * SG; p[A_AG1 + c] = ag[1] * SG; p[A_AG2 + c] = ag[2] * SG;
        p[A_CG0 + c] = cg[0] * SG; p[A_CG1 + c] = cg[1] * SG;
        p[A_BGC + c] = (b_g[i * RC + c] + cg[2]) * SG;
        p[A_BGI + c] = (b_g[i * RC + c] + cg[2] + cg[0] + cg[1]) * SG;
    } else if (idx < L_N * RC + SC) {
        int s = idx - L_N * RC;
        float acc = 0.f;
        for (int i = 0; i < L_N; ++i) acc += b_s[i * SC + s];
        fw[FW_BSUM + s] = acc;
    } else if (idx < 576 + WSBF_N) {
        int j = idx - 576;
        fwh[j] = (short)f2bf(W_s[j]);            // layout [i][s][k] == W_s flat
    } else if (idx < 576 + WSBF_N + W1BF_N) {
        int j = idx - 576 - WSBF_N;
        fwh[WSBF_N + j] = (short)f2bf(W_sk1[j]); // layout [o][s] == W_sk1 flat
    }
}

// ---------------------------------------------------------------------------
// pass1 (per-layer): out_{i+1}[t] = src[t] + b_o + sum_c g_c * wo_c.
// LDS-free; weights wave-uniform -> s_load. No barriers. When Gout != null,
// also stream the gated activations G[t][c] as bf16 (MFMA A-layout, c fastest,
// 64 B / t) so pass2 can skip this layer's gate recompute.
// ---------------------------------------------------------------------------
__global__ __launch_bounds__(NT1) void layer_kernel(
    const float* __restrict__ src, float* __restrict__ dst,
    const float* __restrict__ gwl, const float* __restrict__ wol,
    const float* __restrict__ bol, int d, short* __restrict__ Gout)
{
    int b     = blockIdx.x >> 7;        // T_LEN/CL = 128 chunks
    int chunk = blockIdx.x & 127;
    int t0    = chunk * CL;
    const float* sb = src + (size_t)b * T_LEN;
    float*       db = dst + (size_t)b * T_LEN;
    int tid = threadIdx.x;
    int h   = 2 * d;

    int ta = t0 + tid, tb = ta + NT1;
    v2f s2p, s1p, s0p;
    v2f accp = (v2f){0.f, 0.f};

    short* Ga  = nullptr;
    short* Gb2 = nullptr;
    if (Gout) {
        Ga  = Gout + ((size_t)b * T_LEN + ta) * 32;
        Gb2 = Ga + (size_t)NT1 * 32;
    }

    if (chunk != 0) {
        // interior: chunk>=1 -> ta-2d >= 512-256 >= 0, masks statically 1
        s2p.x = sb[ta];     s2p.y = sb[tb];
        s1p.x = sb[ta - d]; s1p.y = sb[tb - d];
        s0p.x = sb[ta - h]; s0p.y = sb[tb - h];
        for (int c4 = 0; c4 < 8; ++c4) {
            f4 vaf0 = *(const f4*)(gwl + A_AF0 + c4 * 4);
            f4 vaf1 = *(const f4*)(gwl + A_AF1 + c4 * 4);
            f4 vaf2 = *(const f4*)(gwl + A_AF2 + c4 * 4);
            f4 vbfi = *(const f4*)(gwl + A_BFI + c4 * 4);
            f4 vag0 = *(const f4*)(gwl + A_AG0 + c4 * 4);
            f4 vag1 = *(const f4*)(gwl + A_AG1 + c4 * 4);
            f4 vag2 = *(const f4*)(gwl + A_AG2 + c4 * 4);
            f4 vbgi = *(const f4*)(gwl + A_BGI + c4 * 4);
            f4 vwo  = *(const f4*)(wol + c4 * 4);
            float gax[4], gbx[4];
            #pragma unroll
            for (int e = 0; e < 4; ++e) {
                float af0 = vaf0[e], af1 = vaf1[e], af2 = vaf2[e], bfi = vbfi[e];
                float ag0 = vag0[e], ag1 = vag1[e], ag2 = vag2[e], bgi = vbgi[e];
                float woc = vwo[e];
                v2f fp = (v2f){bfi, bfi} + s0p * (v2f){af0, af0} + s1p * (v2f){af1, af1} + s2p * (v2f){af2, af2};
                v2f gp = (v2f){bgi, bgi} + s0p * (v2f){ag0, ag0} + s1p * (v2f){ag1, ag1} + s2p * (v2f){ag2, ag2};
                v2f g;
                g.x = gated_fn(fp.x, gp.x);
                g.y = gated_fn(fp.y, gp.y);
                accp = accp + g * (v2f){woc, woc};
                gax[e] = g.x; gbx[e] = g.y;
            }
            if (Gout) {
                *(uint2*)(Ga  + c4 * 4) = make_uint2(pk2(gax[0], gax[1]), pk2(gax[2], gax[3]));
                *(uint2*)(Gb2 + c4 * 4) = make_uint2(pk2(gbx[0], gbx[1]), pk2(gbx[2], gbx[3]));
            }
        }
    } else {
        // border chunk: guarded taps + mask biases
        v2f m1p, m0p;
        m1p.x = (ta >= d) ? 1.f : 0.f; m1p.y = (tb >= d) ? 1.f : 0.f;
        m0p.x = (ta >= h) ? 1.f : 0.f; m0p.y = (tb >= h) ? 1.f : 0.f;
        s2p.x = sb[ta];
        s2p.y = sb[tb];
        s1p.x = (ta >= d) ? sb[ta - d] : 0.f;
        s1p.y = (tb >= d) ? sb[tb - d] : 0.f;
        s0p.x = (ta >= h) ? sb[ta - h] : 0.f;
        s0p.y = (tb >= h) ? sb[tb - h] : 0.f;
        for (int c4 = 0; c4 < 8; ++c4) {
            f4 vaf0 = *(const f4*)(gwl + A_AF0 + c4 * 4);
            f4 vaf1 = *(const f4*)(gwl + A_AF1 + c4 * 4);
            f4 vaf2 = *(const f4*)(gwl + A_AF2 + c4 * 4);
            f4 vcf0 = *(const f4*)(gwl + A_CF0 + c4 * 4);
            f4 vcf1 = *(const f4*)(gwl + A_CF1 + c4 * 4);
            f4 vbfc = *(const f4*)(gwl + A_BFC + c4 * 4);
            f4 vag0 = *(const f4*)(gwl + A_AG0 + c4 * 4);
            f4 vag1 = *(const f4*)(gwl + A_AG1 + c4 * 4);
            f4 vag2 = *(const f4*)(gwl + A_AG2 + c4 * 4);
            f4 vcg0 = *(const f4*)(gwl + A_CG0 + c4 * 4);
            f4 vcg1 = *(const f4*)(gwl + A_CG1 + c4 * 4);
            f4 vbgc = *(const f4*)(gwl + A_BGC + c4 * 4);
            f4 vwo  = *(const f4*)(wol + c4 * 4);
            float gax[4], gbx[4];
            #pragma unroll
            for (int e = 0; e < 4; ++e) {
                float af0 = vaf0[e], af1 = vaf1[e], af2 = vaf2[e];
                float cf0 = vcf0[e], cf1 = vcf1[e], bfc = vbfc[e];
                float ag0 = vag0[e], ag1 = vag1[e], ag2 = vag2[e];
                float cg0 = vcg0[e], cg1 = vcg1[e], bgc = vbgc[e];
                float woc = vwo[e];
                v2f fp = (v2f){bfc, bfc} + m0p * (v2f){cf0, cf0} + m1p * (v2f){cf1, cf1};
                fp = fp + s0p * (v2f){af0, af0} + s1p * (v2f){af1, af1} + s2p * (v2f){af2, af2};
                v2f gp = (v2f){bgc, bgc} + m0p * (v2f){cg0, cg0} + m1p * (v2f){cg1, cg1};
                gp = gp + s0p * (v2f){ag0, ag0} + s1p * (v2f){ag1, ag1} + s2p * (v2f){ag2, ag2};
                v2f g;
                g.x = gated_fn(fp.x, gp.x);
                g.y = gated_fn(fp.y, gp.y);
                accp = accp + g * (v2f){woc, woc};
                gax[e] = g.x; gbx[e] = g.y;
            }
            if (Gout) {
                *(uint2*)(Ga  + c4 * 4) = make_uint2(pk2(gax[0], gax[1]), pk2(gax[2], gax[3]));
                *(uint2*)(Gb2 + c4 * 4) = make_uint2(pk2(gbx[0], gbx[1]), pk2(gbx[2], gbx[3]));
            }
        }
    }
    float bo = *bol;
    db[ta] = s2p.x + bo + accp.x;
    db[tb] = s2p.y + bo + accp.y;
}

// ---------------------------------------------------------------------------
// pass2: skip-GEMM. Rolled 16-layer loop (R7 structure: 72 VGPR sweet spot).
// Layers i < nG: A-frags read directly from the G buffer pass1 wrote (two
// 16 B loads replace the whole gate recompute). Layers i >= nG: gates
// recomputed in MFMA A-fragment layout (zero LDS / zero barriers in loop).
// Head = second MFMA GEMM (K=64) via bf16 LDS round trip.
// ---------------------------------------------------------------------------
#define SMB_W    0            // 16*448 f32 = 28672 B (layer loop); head reuses [0,18432)
#define SMB_MISC 28672        // bsum[64] b1[64] w2[128] b2[2] = 1032 B
#define SMB_TOT  29712

__global__ __launch_bounds__(256) void pass2_kernel(
    const float* __restrict__ x, const float* __restrict__ streams,
    const float* __restrict__ fw, const short* __restrict__ Wsbf,
    const short* __restrict__ W1bf, const float* __restrict__ b_sk1,
    const float* __restrict__ W_sk2, const float* __restrict__ b_sk2,
    const short* __restrict__ G, int nG, float* __restrict__ out)
{
    __shared__ __align__(16) char smb[SMB_TOT];
    float* sW    = (float*)smb;
    float* sMisc = (float*)(smb + SMB_MISC);

    int tid   = threadIdx.x;
    int b     = blockIdx.x >> 9;
    int chunk = blockIdx.x & 511;
    int t0    = chunk * TS;

    // preload all layer weights (vectorized) + misc
    for (int j = tid; j < (L_N * FW_L) / 4; j += 256)
        ((f4*)sW)[j] = ((const f4*)fw)[j];
    if (tid < 64) { sMisc[tid] = fw[FW_BSUM + tid]; sMisc[64 + tid] = b_sk1[tid]; }
    if (tid < 128) sMisc[128 + tid] = W_sk2[tid];
    if (tid < 2)   sMisc[256 + tid] = b_sk2[tid];
    __syncthreads();

    int wv   = tid >> 6;
    int lane = tid & 63;
    int m    = lane & 15;         // MFMA row-in-tile
    int q    = lane >> 4;         // MFMA quad (k-group: c = q*8..q*8+8)

    int tr0 = t0 + wv * 32 + m;   // my two G rows
    int tr1 = tr0 + 16;

    f4 zero4 = {0.f, 0.f, 0.f, 0.f};
    f4 acc[2][4];
    #pragma unroll
    for (int tt = 0; tt < 2; ++tt)
        #pragma unroll
        for (int st = 0; st < 4; ++st) acc[tt][st] = zero4;

    const float* xb = x + (size_t)b * T_LEN;
    for (int i = 0; i < L_N; ++i) {
        const int d = 1 << (i & 7);

        bf8 bfrag[4];
        #pragma unroll
        for (int st = 0; st < 4; ++st)
            bfrag[st] = *(const bf8*)(Wsbf + i * (SC * RC) + (st * 16 + m) * RC + q * 8);

        bf8 a0, a1;
        if (i < nG) {
            // gates precomputed by pass1 (bit-identical to recompute)
            const short* Gl = G + (size_t)i * BT * 32 + (size_t)b * T_LEN * 32;
            a0 = *(const bf8*)(Gl + (size_t)tr0 * 32 + q * 8);
            a1 = *(const bf8*)(Gl + (size_t)tr1 * 32 + q * 8);
        } else {
            const float* src = (i == 0) ? xb
                                        : (streams + (size_t)(i - 1) * BT + (size_t)b * T_LEN);
            const float* w = sW + i * FW_L + q * 8;
            unsigned uf[2][4];
            if (t0 >= 2 * d) {
                // interior: all taps in range, masks statically 1
                float s2a = src[tr0], s1a = src[tr0 - d], s0a = src[tr0 - 2 * d];
                float s2b = src[tr1], s1b = src[tr1 - d], s0b = src[tr1 - 2 * d];
                #pragma unroll
                for (int hc = 0; hc < 2; ++hc) {
                    const float* wc = w + hc * 4;
                    f4 af0 = *(const f4*)(wc + A_AF0), af1 = *(const f4*)(wc + A_AF1), af2 = *(const f4*)(wc + A_AF2);
                    f4 bfi = *(const f4*)(wc + A_BFI);
                    f4 ag0 = *(const f4*)(wc + A_AG0), ag1 = *(const f4*)(wc + A_AG1), ag2 = *(const f4*)(wc + A_AG2);
                    f4 bgi = *(const f4*)(wc + A_BGI);
                    f4 fpa = bfi + s0a * af0 + s1a * af1 + s2a * af2;
                    f4 gpa = bgi + s0a * ag0 + s1a * ag1 + s2a * ag2;
                    f4 fpb = bfi + s0b * af0 + s1b * af1 + s2b * af2;
                    f4 gpb = bgi + s0b * ag0 + s1b * ag1 + s2b * ag2;
                    uf[0][hc * 2 + 0] = pk2(gated_fn(fpa[0], gpa[0]), gated_fn(fpa[1], gpa[1]));
                    uf[0][hc * 2 + 1] = pk2(gated_fn(fpa[2], gpa[2]), gated_fn(fpa[3], gpa[3]));
                    uf[1][hc * 2 + 0] = pk2(gated_fn(fpb[0], gpb[0]), gated_fn(fpb[1], gpb[1]));
                    uf[1][hc * 2 + 1] = pk2(gated_fn(fpb[2], gpb[2]), gated_fn(fpb[3], gpb[3]));
                }
            } else {
                // border (t0 < 2d: <=16 blocks/layer): guarded taps + mask biases
                float m1a = (tr0 >= d) ? 1.f : 0.f, m0a = (tr0 >= 2 * d) ? 1.f : 0.f;
                float m1b = (tr1 >= d) ? 1.f : 0.f, m0b = (tr1 >= 2 * d) ? 1.f : 0.f;
                float s2a = src[tr0];
                float s1a = (tr0 >= d)     ? src[tr0 - d]     : 0.f;
                float s0a = (tr0 >= 2 * d) ? src[tr0 - 2 * d] : 0.f;
                float s2b = src[tr1];
                float s1b = (tr1 >= d)     ? src[tr1 - d]     : 0.f;
                float s0b = (tr1 >= 2 * d) ? src[tr1 - 2 * d] : 0.f;
                #pragma unroll
                for (int hc = 0; hc < 2; ++hc) {
                    const float* wc = w + hc * 4;
                    f4 af0 = *(const f4*)(wc + A_AF0), af1 = *(const f4*)(wc + A_AF1), af2 = *(const f4*)(wc + A_AF2);
                    f4 cf0 = *(const f4*)(wc + A_CF0), cf1 = *(const f4*)(wc + A_CF1), bfc = *(const f4*)(wc + A_BFC);
                    f4 ag0 = *(const f4*)(wc + A_AG0), ag1 = *(const f4*)(wc + A_AG1), ag2 = *(const f4*)(wc + A_AG2);
                    f4 cg0 = *(const f4*)(wc + A_CG0), cg1 = *(const f4*)(wc + A_CG1), bgc = *(const f4*)(wc + A_BGC);
                    f4 fpa = bfc + m0a * cf0 + m1a * cf1 + s0a * af0 + s1a * af1 + s2a * af2;
                    f4 gpa = bgc + m0a * cg0 + m1a * cg1 + s0a * ag0 + s1a * ag1 + s2a * ag2;
                    f4 fpb = bfc + m0b * cf0 + m1b * cf1 + s0b * af0 + s1b * af1 + s2b * af2;
                    f4 gpb = bgc + m0b * cg0 + m1b * cg1 + s0b * ag0 + s1b * ag1 + s2b * ag2;
                    uf[0][hc * 2 + 0] = pk2(gated_fn(fpa[0], gpa[0]), gated_fn(fpa[1], gpa[1]));
                    uf[0][hc * 2 + 1] = pk2(gated_fn(fpa[2], gpa[2]), gated_fn(fpa[3], gpa[3]));
                    uf[1][hc * 2 + 0] = pk2(gated_fn(fpb[0], gpb[0]), gated_fn(fpb[1], gpb[1]));
                    uf[1][hc * 2 + 1] = pk2(gated_fn(fpb[2], gpb[2]), gated_fn(fpb[3], gpb[3]));
                }
            }
            a0 = mk_bf8(uf[0][0], uf[0][1], uf[0][2], uf[0][3]);
            a1 = mk_bf8(uf[1][0], uf[1][1], uf[1][2], uf[1][3]);
        }

        #pragma unroll
        for (int st = 0; st < 4; ++st) {
            acc[0][st] = MFMA16(a0, bfrag[st], acc[0][st]);
            acc[1][st] = MFMA16(a1, bfrag[st], acc[1][st]);
        }
    }

    // ---- head ----
    __syncthreads();   // all waves done reading sW; region reusable
    // skip (+Bsum) -> bf16 LDS [t][s], stride 144 B
    #pragma unroll
    for (int tt = 0; tt < 2; ++tt) {
        int tb = (wv * 2 + tt) * 16 + q * 4;
        #pragma unroll
        for (int st = 0; st < 4; ++st) {
            int s = st * 16 + m;
            float bs = sMisc[s];
            #pragma unroll
            for (int r = 0; r < 4; ++r)
                *(unsigned short*)(smb + (tb + r) * 144 + s * 2) = f2bf(acc[tt][st][r] + bs);
        }
    }
    // W1 B-fragments from global bf16 [o][s]
    bf8 w1f[4][2];
    #pragma unroll
    for (int ot = 0; ot < 4; ++ot)
        #pragma unroll
        for (int kc = 0; kc < 2; ++kc)
            w1f[ot][kc] = *(const bf8*)(W1bf + (ot * 16 + m) * SC + kc * 32 + q * 8);
    __syncthreads();   // skip matrix ready

    f4 hacc[2][4];
    #pragma unroll
    for (int tt = 0; tt < 2; ++tt)
        #pragma unroll
        for (int ot = 0; ot < 4; ++ot) hacc[tt][ot] = zero4;
    #pragma unroll
    for (int tt = 0; tt < 2; ++tt) {
        int trow = (wv * 2 + tt) * 16 + m;
        #pragma unroll
        for (int kc = 0; kc < 2; ++kc) {
            bf8 afrag = *(const bf8*)(smb + trow * 144 + kc * 64 + q * 16);
            #pragma unroll
            for (int ot = 0; ot < 4; ++ot)
                hacc[tt][ot] = MFMA16(afrag, w1f[ot][kc], hacc[tt][ot]);
        }
    }

    // epilogue: relu + W_sk2 contraction + cross-lane reduce over o (col bits)
    float p0[2][4], p1[2][4];
    #pragma unroll
    for (int tt = 0; tt < 2; ++tt)
        #pragma unroll
        for (int r = 0; r < 4; ++r) { p0[tt][r] = 0.f; p1[tt][r] = 0.f; }
    #pragma unroll
    for (int ot = 0; ot < 4; ++ot) {
        int o = ot * 16 + m;
        float w20 = sMisc[128 + o], w21 = sMisc[192 + o], b1v = sMisc[64 + o];
        #pragma unroll
        for (int tt = 0; tt < 2; ++tt)
            #pragma unroll
            for (int r = 0; r < 4; ++r) {
                float hv = fmaxf(hacc[tt][ot][r] + b1v, 0.f);
                p0[tt][r] = fmaf(w20, hv, p0[tt][r]);
                p1[tt][r] = fmaf(w21, hv, p1[tt][r]);
            }
    }
    #pragma unroll
    for (int msk = 1; msk <= 8; msk <<= 1) {
        #pragma unroll
        for (int tt = 0; tt < 2; ++tt)
            #pragma unroll
            for (int r = 0; r < 4; ++r) {
                p0[tt][r] += __shfl_xor(p0[tt][r], msk);
                p1[tt][r] += __shfl_xor(p1[tt][r], msk);
            }
    }
    if (m == 0) {
        float b20 = sMisc[256], b21 = sMisc[257];
        #pragma unroll
        for (int tt = 0; tt < 2; ++tt) {
            int t = t0 + (wv * 2 + tt) * 16 + q * 4;
            size_t gi = (size_t)b * T_LEN + t;
            f4 mv, sv;
            #pragma unroll
            for (int r = 0; r < 4; ++r) {
                mv[r] = p0[tt][r] + b20;
                sv[r] = __expf(0.5f * (p1[tt][r] + b21));
            }
            *(f4*)(out + gi)      = mv;
            *(f4*)(out + BT + gi) = sv;
        }
    }
}

// ---------------------------------------------------------------------------
extern "C" void kernel_launch(void* const* d_in, const int* in_sizes, int n_in,
                              void* d_out, int out_size, void* d_ws, size_t ws_size,
                              hipStream_t stream) {
    const float* x     = (const float*)d_in[0];
    const float* W_in  = (const float*)d_in[1];
    const float* b_in  = (const float*)d_in[2];
    const float* W_f   = (const float*)d_in[3];
    const float* b_f   = (const float*)d_in[4];
    const float* W_g   = (const float*)d_in[5];
    const float* b_g   = (const float*)d_in[6];
    const float* W_s   = (const float*)d_in[7];
    const float* b_s   = (const float*)d_in[8];
    const float* W_o   = (const float*)d_in[9];
    const float* b_o   = (const float*)d_in[10];
    const float* W_sk1 = (const float*)d_in[11];
    const float* b_sk1 = (const float*)d_in[12];
    const float* W_sk2 = (const float*)d_in[13];
    const float* b_sk2 = (const float*)d_in[14];
    float* outp = (float*)d_out;

    float* streams = (float*)d_ws;                 // 15*BT floats (30 MB)
    float* fw      = streams + (size_t)15 * BT;    // FW_F32 floats
    short* fwh     = (short*)(fw + FW_F32);        // bf16 tables
    short* G       = fwh + WSBF_N + W1BF_N;        // up to 15 layers of bf16 G

    // adaptive: store G for as many layers as the workspace fits
    size_t base = (size_t)15 * BT * 4 + (size_t)FW_F32 * 4
                + (size_t)(WSBF_N + W1BF_N) * 2;
    size_t perG = (size_t)BT * RC * 2;             // 33.5 MB per layer
    int nG = 0;
    if (ws_size > base) {
        size_t fit = (ws_size - base) / perG;
        nG = (fit > 15) ? 15 : (int)fit;
    }

    int prep_items = 576 + WSBF_N + W1BF_N;
    prep_kernel<<<(prep_items + 255) / 256, 256, 0, stream>>>(
        W_f, W_g, W_in, b_in, b_f, b_g, b_s, W_s, W_sk1, fw, fwh);
    for (int i = 0; i < 15; ++i) {
        int d = 1 << (i & 7);
        const float* src = (i == 0) ? x : streams + (size_t)(i - 1) * BT;
        short* Gout = (i < nG) ? (G + (size_t)i * BT * RC) : nullptr;
        layer_kernel<<<B_N * (T_LEN / CL), NT1, 0, stream>>>(
            src, streams + (size_t)i * BT, fw + i * FW_L, W_o + i * 32, b_o + i, d, Gout);
    }
    pass2_kernel<<<B_N * (T_LEN / TS), 256, 0, stream>>>(
        x, streams, fw, fwh, fwh + WSBF_N, b_sk1, W_sk2, b_sk2, G, nG, outp);
}

// Round 13
// 406.501 us; speedup vs baseline: 1.2386x; 1.2386x over previous
//
#include <hip/hip_runtime.h>
#include <hip/hip_bf16.h>
#include <math.h>

#define T_LEN 65536
#define B_N   8
#define BT    (T_LEN * B_N)
#define L_N   16
#define RC    32
#define SC    64

// pass1: per-layer dispatches. 256 thr x 2 elems = 512 outputs/block.
#define NT1   256
#define CL    512

// pass2 tiling
#define TS    128

// folded-weight array offsets (per layer, 14 arrays of 32)
#define A_AF0 0
#define A_AF1 32
#define A_AF2 64
#define A_CF0 96
#define A_CF1 128
#define A_BFC 160
#define A_AG0 192
#define A_AG1 224
#define A_AG2 256
#define A_CG0 288
#define A_CG1 320
#define A_BGC 352
#define A_BFI 384            // bfc+cf0+cf1 (interior: masks statically 1)
#define A_BGI 416            // bgc+cg0+cg1
#define FW_L  448
#define FW_BSUM (L_N * FW_L)     // 7168, +64
#define FW_F32  (FW_BSUM + 64)   // float count; bf16 tables follow as shorts
#define WSBF_N  (L_N * SC * RC)   // 32768 shorts
#define W1BF_N  (SC * SC)         // 4096 shorts

typedef float v2f __attribute__((ext_vector_type(2)));
typedef __attribute__((ext_vector_type(4))) float f4;
typedef __attribute__((ext_vector_type(8))) short bf8;

#define MFMA16(a, b, c) __builtin_amdgcn_mfma_f32_16x16x32_bf16(a, b, c, 0, 0, 0)

__device__ __forceinline__ float fast_rcp(float x) { return __builtin_amdgcn_rcpf(x); }

// fp,gp arrive pre-scaled by 2*log2(e) / log2(e) (folded in prep), so the
// hardware 2^x op is used directly: E = e^{2f}, F = e^{g}.
__device__ __forceinline__ float gated_fn(float fp, float gp) {
    float E = __builtin_amdgcn_exp2f(fp);
    float F = __builtin_amdgcn_exp2f(gp);
    return (E - 1.f) * F * fast_rcp((E + 1.f) * (F + 1.f));
}

// f32 -> bf16 round-to-nearest-even (values finite; no NaN handling needed)
__device__ __forceinline__ unsigned short f2bf(float f) {
    unsigned u = __float_as_uint(f);
    u += 0x7fffu + ((u >> 16) & 1u);
    return (unsigned short)(u >> 16);
}

__device__ __forceinline__ unsigned pk2(float lo, float hi) {
    __hip_bfloat162 h = __float22bfloat162_rn(make_float2(lo, hi));
    unsigned u; __builtin_memcpy(&u, &h, 4); return u;
}

__device__ __forceinline__ bf8 mk_bf8(unsigned a, unsigned b, unsigned c, unsigned d) {
    unsigned v[4] = {a, b, c, d};
    bf8 r; __builtin_memcpy(&r, v, 16); return r;
}

// ---------------------------------------------------------------------------
// prep: fold gate weights (pre-scaled for exp2); Bsum; bf16 W_s / W_sk1.
// ---------------------------------------------------------------------------
__global__ __launch_bounds__(256) void prep_kernel(
    const float* __restrict__ W_f, const float* __restrict__ W_g,
    const float* __restrict__ W_in, const float* __restrict__ b_in,
    const float* __restrict__ b_f, const float* __restrict__ b_g,
    const float* __restrict__ b_s, const float* __restrict__ W_s,
    const float* __restrict__ W_sk1, float* __restrict__ fw,
    short* __restrict__ fwh)
{
    const float SF = 2.88539008177792681472f;  // 2*log2(e)
    const float SG = 1.44269504088896340736f;  // log2(e)
    int idx = blockIdx.x * 256 + threadIdx.x;
    if (idx < L_N * RC) {
        int i = idx >> 5, c = idx & 31;
        float af[3] = {0,0,0}, cf[3] = {0,0,0}, ag[3] = {0,0,0}, cg[3] = {0,0,0};
        for (int cin = 0; cin < RC; ++cin) {
            float wi = W_in[i * RC + cin];
            float bi = b_in[i * RC + cin];
            #pragma unroll
            for (int k = 0; k < 3; ++k) {
                float wf = W_f[((i * RC + c) * RC + cin) * 3 + k];
                float wg = W_g[((i * RC + c) * RC + cin) * 3 + k];
                af[k] = fmaf(wf, wi, af[k]);
                cf[k] = fmaf(wf, bi, cf[k]);
                ag[k] = fmaf(wg, wi, ag[k]);
                cg[k] = fmaf(wg, bi, cg[k]);
            }
        }
        float* p = fw + i * FW_L;
        p[A_AF0 + c] = af[0] * SF; p[A_AF1 + c] = af[1] * SF; p[A_AF2 + c] = af[2] * SF;
        p[A_CF0 + c] = cf[0] * SF; p[A_CF1 + c] = cf[1] * SF;
        p[A_BFC + c] = (b_f[i * RC + c] + cf[2]) * SF;
        p[A_BFI + c] = (b_f[i * RC + c] + cf[2] + cf[0] + cf[1]) * SF;
        p[A_AG0 + c] = ag[0] * SG; p[A_AG1 + c] = ag[1] * SG; p[A_AG2 + c] = ag[2] * SG;
        p[A_CG0 + c] = cg[0] * SG; p[A_CG1 + c] = cg[1] * SG;
        p[A_BGC + c] = (b_g[i * RC + c] + cg[2]) * SG;
        p[A_BGI + c] = (b_g[i * RC + c] + cg[2] + cg[0] + cg[1]) * SG;
    } else if (idx < L_N * RC + SC) {
        int s = idx - L_N * RC;
        float acc = 0.f;
        for (int i = 0; i < L_N; ++i) acc += b_s[i * SC + s];
        fw[FW_BSUM + s] = acc;
    } else if (idx < 576 + WSBF_N) {
        int j = idx - 576;
        fwh[j] = (short)f2bf(W_s[j]);            // layout [i][s][k] == W_s flat
    } else if (idx < 576 + WSBF_N + W1BF_N) {
        int j = idx - 576 - WSBF_N;
        fwh[WSBF_N + j] = (short)f2bf(W_sk1[j]); // layout [o][s] == W_sk1 flat
    }
}

// ---------------------------------------------------------------------------
// pass1 (per-layer): out_{i+1}[t] = src[t] + b_o + sum_c g_c * wo_c.
// LDS-free: taps straight from global (stream is L2/L3-resident); gate
// weights are wave-uniform -> direct global reads compile to s_load
// (SGPR operands, off the VALU/LDS pipes). No barriers at all.
// ---------------------------------------------------------------------------
__global__ __launch_bounds__(NT1) void layer_kernel(
    const float* __restrict__ src, float* __restrict__ dst,
    const float* __restrict__ gwl, const float* __restrict__ wol,
    const float* __restrict__ bol, int d)
{
    int b     = blockIdx.x >> 7;        // T_LEN/CL = 128 chunks
    int chunk = blockIdx.x & 127;
    int t0    = chunk * CL;
    const float* sb = src + (size_t)b * T_LEN;
    float*       db = dst + (size_t)b * T_LEN;
    int tid = threadIdx.x;
    int h   = 2 * d;

    int ta = t0 + tid, tb = ta + NT1;
    v2f s2p, s1p, s0p;
    v2f accp = (v2f){0.f, 0.f};

    if (chunk != 0) {
        // interior: chunk>=1 -> ta-2d >= 512-256 >= 0, masks statically 1
        s2p.x = sb[ta];     s2p.y = sb[tb];
        s1p.x = sb[ta - d]; s1p.y = sb[tb - d];
        s0p.x = sb[ta - h]; s0p.y = sb[tb - h];
        for (int c4 = 0; c4 < 8; ++c4) {
            f4 vaf0 = *(const f4*)(gwl + A_AF0 + c4 * 4);
            f4 vaf1 = *(const f4*)(gwl + A_AF1 + c4 * 4);
            f4 vaf2 = *(const f4*)(gwl + A_AF2 + c4 * 4);
            f4 vbfi = *(const f4*)(gwl + A_BFI + c4 * 4);
            f4 vag0 = *(const f4*)(gwl + A_AG0 + c4 * 4);
            f4 vag1 = *(const f4*)(gwl + A_AG1 + c4 * 4);
            f4 vag2 = *(const f4*)(gwl + A_AG2 + c4 * 4);
            f4 vbgi = *(const f4*)(gwl + A_BGI + c4 * 4);
            f4 vwo  = *(const f4*)(wol + c4 * 4);
            #pragma unroll
            for (int e = 0; e < 4; ++e) {
                float af0 = vaf0[e], af1 = vaf1[e], af2 = vaf2[e], bfi = vbfi[e];
                float ag0 = vag0[e], ag1 = vag1[e], ag2 = vag2[e], bgi = vbgi[e];
                float woc = vwo[e];
                v2f fp = (v2f){bfi, bfi} + s0p * (v2f){af0, af0} + s1p * (v2f){af1, af1} + s2p * (v2f){af2, af2};
                v2f gp = (v2f){bgi, bgi} + s0p * (v2f){ag0, ag0} + s1p * (v2f){ag1, ag1} + s2p * (v2f){ag2, ag2};
                v2f g;
                g.x = gated_fn(fp.x, gp.x);
                g.y = gated_fn(fp.y, gp.y);
                accp = accp + g * (v2f){woc, woc};
            }
        }
    } else {
        // border chunk: guarded taps + mask biases
        v2f m1p, m0p;
        m1p.x = (ta >= d) ? 1.f : 0.f; m1p.y = (tb >= d) ? 1.f : 0.f;
        m0p.x = (ta >= h) ? 1.f : 0.f; m0p.y = (tb >= h) ? 1.f : 0.f;
        s2p.x = sb[ta];
        s2p.y = sb[tb];
        s1p.x = (ta >= d) ? sb[ta - d] : 0.f;
        s1p.y = (tb >= d) ? sb[tb - d] : 0.f;
        s0p.x = (ta >= h) ? sb[ta - h] : 0.f;
        s0p.y = (tb >= h) ? sb[tb - h] : 0.f;
        for (int c4 = 0; c4 < 8; ++c4) {
            f4 vaf0 = *(const f4*)(gwl + A_AF0 + c4 * 4);
            f4 vaf1 = *(const f4*)(gwl + A_AF1 + c4 * 4);
            f4 vaf2 = *(const f4*)(gwl + A_AF2 + c4 * 4);
            f4 vcf0 = *(const f4*)(gwl + A_CF0 + c4 * 4);
            f4 vcf1 = *(const f4*)(gwl + A_CF1 + c4 * 4);
            f4 vbfc = *(const f4*)(gwl + A_BFC + c4 * 4);
            f4 vag0 = *(const f4*)(gwl + A_AG0 + c4 * 4);
            f4 vag1 = *(const f4*)(gwl + A_AG1 + c4 * 4);
            f4 vag2 = *(const f4*)(gwl + A_AG2 + c4 * 4);
            f4 vcg0 = *(const f4*)(gwl + A_CG0 + c4 * 4);
            f4 vcg1 = *(const f4*)(gwl + A_CG1 + c4 * 4);
            f4 vbgc = *(const f4*)(gwl + A_BGC + c4 * 4);
            f4 vwo  = *(const f4*)(wol + c4 * 4);
            #pragma unroll
            for (int e = 0; e < 4; ++e) {
                float af0 = vaf0[e], af1 = vaf1[e], af2 = vaf2[e];
                float cf0 = vcf0[e], cf1 = vcf1[e], bfc = vbfc[e];
                float ag0 = vag0[e], ag1 = vag1[e], ag2 = vag2[e];
                float cg0 = vcg0[e], cg1 = vcg1[e], bgc = vbgc[e];
                float woc = vwo[e];
                v2f fp = (v2f){bfc, bfc} + m0p * (v2f){cf0, cf0} + m1p * (v2f){cf1, cf1};
                fp = fp + s0p * (v2f){af0, af0} + s1p * (v2f){af1, af1} + s2p * (v2f){af2, af2};
                v2f gp = (v2f){bgc, bgc} + m0p * (v2f){cg0, cg0} + m1p * (v2f){cg1, cg1};
                gp = gp + s0p * (v2f){ag0, ag0} + s1p * (v2f){ag1, ag1} + s2p * (v2f){ag2, ag2};
                v2f g;
                g.x = gated_fn(fp.x, gp.x);
                g.y = gated_fn(fp.y, gp.y);
                accp = accp + g * (v2f){woc, woc};
            }
        }
    }
    float bo = *bol;
    db[ta] = s2p.x + bo + accp.x;
    db[tb] = s2p.y + bo + accp.y;
}

// ---------------------------------------------------------------------------
// pass2: gate phase computed directly in MFMA A-fragment layout.
// Thread (wave wv, lane m+16q) computes G[t0+wv*32+tt*16+m][c=q*8..q*8+8]
// for tt=0,1 -> the exact bf8 A-frags it feeds to MFMA. Zero LDS / zero
// barriers in the 16-layer loop; taps straight from global (L2/L3-resident);
// all layer weights preloaded to LDS once (region reused by the head after
// a barrier). Rolled loop: 72 VGPR sweet spot (full unroll and manual
// prefetch both regressed via register pressure -- measured R8/R10).
// Head = second MFMA GEMM (K=64) via bf16 LDS round trip.
// ---------------------------------------------------------------------------
#define SMB_W    0            // 16*448 f32 = 28672 B (layer loop); head reuses [0,18432)
#define SMB_MISC 28672        // bsum[64] b1[64] w2[128] b2[2] = 1032 B
#define SMB_TOT  29712

__global__ __launch_bounds__(256) void pass2_kernel(
    const float* __restrict__ x, const float* __restrict__ streams,
    const float* __restrict__ fw, const short* __restrict__ Wsbf,
    const short* __restrict__ W1bf, const float* __restrict__ b_sk1,
    const float* __restrict__ W_sk2, const float* __restrict__ b_sk2,
    float* __restrict__ out)
{
    __shared__ __align__(16) char smb[SMB_TOT];
    float* sW    = (float*)smb;
    float* sMisc = (float*)(smb + SMB_MISC);

    int tid   = threadIdx.x;
    int b     = blockIdx.x >> 9;
    int chunk = blockIdx.x & 511;
    int t0    = chunk * TS;

    // preload all layer weights (vectorized) + misc
    for (int j = tid; j < (L_N * FW_L) / 4; j += 256)
        ((f4*)sW)[j] = ((const f4*)fw)[j];
    if (tid < 64) { sMisc[tid] = fw[FW_BSUM + tid]; sMisc[64 + tid] = b_sk1[tid]; }
    if (tid < 128) sMisc[128 + tid] = W_sk2[tid];
    if (tid < 2)   sMisc[256 + tid] = b_sk2[tid];
    __syncthreads();

    int wv   = tid >> 6;
    int lane = tid & 63;
    int m    = lane & 15;         // MFMA row-in-tile
    int q    = lane >> 4;         // MFMA quad (k-group: c = q*8..q*8+8)

    int tr0 = t0 + wv * 32 + m;   // my two G rows
    int tr1 = tr0 + 16;

    f4 zero4 = {0.f, 0.f, 0.f, 0.f};
    f4 acc[2][4];
    #pragma unroll
    for (int tt = 0; tt < 2; ++tt)
        #pragma unroll
        for (int st = 0; st < 4; ++st) acc[tt][st] = zero4;

    const float* xb = x + (size_t)b * T_LEN;
    for (int i = 0; i < L_N; ++i) {
        const int d = 1 << (i & 7);
        const float* src = (i == 0) ? xb
                                    : (streams + (size_t)(i - 1) * BT + (size_t)b * T_LEN);
        const float* w = sW + i * FW_L + q * 8;

        bf8 bfrag[4];
        #pragma unroll
        for (int st = 0; st < 4; ++st)
            bfrag[st] = *(const bf8*)(Wsbf + i * (SC * RC) + (st * 16 + m) * RC + q * 8);

        unsigned uf[2][4];
        if (t0 >= 2 * d) {
            // interior: all taps in range, masks statically 1
            float s2a = src[tr0], s1a = src[tr0 - d], s0a = src[tr0 - 2 * d];
            float s2b = src[tr1], s1b = src[tr1 - d], s0b = src[tr1 - 2 * d];
            #pragma unroll
            for (int hc = 0; hc < 2; ++hc) {
                const float* wc = w + hc * 4;
                f4 af0 = *(const f4*)(wc + A_AF0), af1 = *(const f4*)(wc + A_AF1), af2 = *(const f4*)(wc + A_AF2);
                f4 bfi = *(const f4*)(wc + A_BFI);
                f4 ag0 = *(const f4*)(wc + A_AG0), ag1 = *(const f4*)(wc + A_AG1), ag2 = *(const f4*)(wc + A_AG2);
                f4 bgi = *(const f4*)(wc + A_BGI);
                f4 fpa = bfi + s0a * af0 + s1a * af1 + s2a * af2;
                f4 gpa = bgi + s0a * ag0 + s1a * ag1 + s2a * ag2;
                f4 fpb = bfi + s0b * af0 + s1b * af1 + s2b * af2;
                f4 gpb = bgi + s0b * ag0 + s1b * ag1 + s2b * ag2;
                uf[0][hc * 2 + 0] = pk2(gated_fn(fpa[0], gpa[0]), gated_fn(fpa[1], gpa[1]));
                uf[0][hc * 2 + 1] = pk2(gated_fn(fpa[2], gpa[2]), gated_fn(fpa[3], gpa[3]));
                uf[1][hc * 2 + 0] = pk2(gated_fn(fpb[0], gpb[0]), gated_fn(fpb[1], gpb[1]));
                uf[1][hc * 2 + 1] = pk2(gated_fn(fpb[2], gpb[2]), gated_fn(fpb[3], gpb[3]));
            }
        } else {
            // border (t0 < 2d: <=16 blocks/layer): guarded taps + mask biases
            float m1a = (tr0 >= d) ? 1.f : 0.f, m0a = (tr0 >= 2 * d) ? 1.f : 0.f;
            float m1b = (tr1 >= d) ? 1.f : 0.f, m0b = (tr1 >= 2 * d) ? 1.f : 0.f;
            float s2a = src[tr0];
            float s1a = (tr0 >= d)     ? src[tr0 - d]     : 0.f;
            float s0a = (tr0 >= 2 * d) ? src[tr0 - 2 * d] : 0.f;
            float s2b = src[tr1];
            float s1b = (tr1 >= d)     ? src[tr1 - d]     : 0.f;
            float s0b = (tr1 >= 2 * d) ? src[tr1 - 2 * d] : 0.f;
            #pragma unroll
            for (int hc = 0; hc < 2; ++hc) {
                const float* wc = w + hc * 4;
                f4 af0 = *(const f4*)(wc + A_AF0), af1 = *(const f4*)(wc + A_AF1), af2 = *(const f4*)(wc + A_AF2);
                f4 cf0 = *(const f4*)(wc + A_CF0), cf1 = *(const f4*)(wc + A_CF1), bfc = *(const f4*)(wc + A_BFC);
                f4 ag0 = *(const f4*)(wc + A_AG0), ag1 = *(const f4*)(wc + A_AG1), ag2 = *(const f4*)(wc + A_AG2);
                f4 cg0 = *(const f4*)(wc + A_CG0), cg1 = *(const f4*)(wc + A_CG1), bgc = *(const f4*)(wc + A_BGC);
                f4 fpa = bfc + m0a * cf0 + m1a * cf1 + s0a * af0 + s1a * af1 + s2a * af2;
                f4 gpa = bgc + m0a * cg0 + m1a * cg1 + s0a * ag0 + s1a * ag1 + s2a * ag2;
                f4 fpb = bfc + m0b * cf0 + m1b * cf1 + s0b * af0 + s1b * af1 + s2b * af2;
                f4 gpb = bgc + m0b * cg0 + m1b * cg1 + s0b * ag0 + s1b * ag1 + s2b * ag2;
                uf[0][hc * 2 + 0] = pk2(gated_fn(fpa[0], gpa[0]), gated_fn(fpa[1], gpa[1]));
                uf[0][hc * 2 + 1] = pk2(gated_fn(fpa[2], gpa[2]), gated_fn(fpa[3], gpa[3]));
                uf[1][hc * 2 + 0] = pk2(gated_fn(fpb[0], gpb[0]), gated_fn(fpb[1], gpb[1]));
                uf[1][hc * 2 + 1] = pk2(gated_fn(fpb[2], gpb[2]), gated_fn(fpb[3], gpb[3]));
            }
        }

        bf8 a0 = mk_bf8(uf[0][0], uf[0][1], uf[0][2], uf[0][3]);
        bf8 a1 = mk_bf8(uf[1][0], uf[1][1], uf[1][2], uf[1][3]);
        #pragma unroll
        for (int st = 0; st < 4; ++st) {
            acc[0][st] = MFMA16(a0, bfrag[st], acc[0][st]);
            acc[1][st] = MFMA16(a1, bfrag[st], acc[1][st]);
        }
    }

    // ---- head ----
    __syncthreads();   // all waves done reading sW; region reusable
    // skip (+Bsum) -> bf16 LDS [t][s], stride 144 B
    #pragma unroll
    for (int tt = 0; tt < 2; ++tt) {
        int tb = (wv * 2 + tt) * 16 + q * 4;
        #pragma unroll
        for (int st = 0; st < 4; ++st) {
            int s = st * 16 + m;
            float bs = sMisc[s];
            #pragma unroll
            for (int r = 0; r < 4; ++r)
                *(unsigned short*)(smb + (tb + r) * 144 + s * 2) = f2bf(acc[tt][st][r] + bs);
        }
    }
    // W1 B-fragments from global bf16 [o][s]
    bf8 w1f[4][2];
    #pragma unroll
    for (int ot = 0; ot < 4; ++ot)
        #pragma unroll
        for (int kc = 0; kc < 2; ++kc)
            w1f[ot][kc] = *(const bf8*)(W1bf + (ot * 16 + m) * SC + kc * 32 + q * 8);
    __syncthreads();   // skip matrix ready

    f4 hacc[2][4];
    #pragma unroll
    for (int tt = 0; tt < 2; ++tt)
        #pragma unroll
        for (int ot = 0; ot < 4; ++ot) hacc[tt][ot] = zero4;
    #pragma unroll
    for (int tt = 0; tt < 2; ++tt) {
        int trow = (wv * 2 + tt) * 16 + m;
        #pragma unroll
        for (int kc = 0; kc < 2; ++kc) {
            bf8 afrag = *(const bf8*)(smb + trow * 144 + kc * 64 + q * 16);
            #pragma unroll
            for (int ot = 0; ot < 4; ++ot)
                hacc[tt][ot] = MFMA16(afrag, w1f[ot][kc], hacc[tt][ot]);
        }
    }

    // epilogue: relu + W_sk2 contraction + cross-lane reduce over o (col bits)
    float p0[2][4], p1[2][4];
    #pragma unroll
    for (int tt = 0; tt < 2; ++tt)
        #pragma unroll
        for (int r = 0; r < 4; ++r) { p0[tt][r] = 0.f; p1[tt][r] = 0.f; }
    #pragma unroll
    for (int ot = 0; ot < 4; ++ot) {
        int o = ot * 16 + m;
        float w20 = sMisc[128 + o], w21 = sMisc[192 + o], b1v = sMisc[64 + o];
        #pragma unroll
        for (int tt = 0; tt < 2; ++tt)
            #pragma unroll
            for (int r = 0; r < 4; ++r) {
                float hv = fmaxf(hacc[tt][ot][r] + b1v, 0.f);
                p0[tt][r] = fmaf(w20, hv, p0[tt][r]);
                p1[tt][r] = fmaf(w21, hv, p1[tt][r]);
            }
    }
    #pragma unroll
    for (int msk = 1; msk <= 8; msk <<= 1) {
        #pragma unroll
        for (int tt = 0; tt < 2; ++tt)
            #pragma unroll
            for (int r = 0; r < 4; ++r) {
                p0[tt][r] += __shfl_xor(p0[tt][r], msk);
                p1[tt][r] += __shfl_xor(p1[tt][r], msk);
            }
    }
    if (m == 0) {
        float b20 = sMisc[256], b21 = sMisc[257];
        #pragma unroll
        for (int tt = 0; tt < 2; ++tt) {
            int t = t0 + (wv * 2 + tt) * 16 + q * 4;
            size_t gi = (size_t)b * T_LEN + t;
            f4 mv, sv;
            #pragma unroll
            for (int r = 0; r < 4; ++r) {
                mv[r] = p0[tt][r] + b20;
                sv[r] = __expf(0.5f * (p1[tt][r] + b21));
            }
            *(f4*)(out + gi)      = mv;
            *(f4*)(out + BT + gi) = sv;
        }
    }
}

// ---------------------------------------------------------------------------
extern "C" void kernel_launch(void* const* d_in, const int* in_sizes, int n_in,
                              void* d_out, int out_size, void* d_ws, size_t ws_size,
                              hipStream_t stream) {
    const float* x     = (const float*)d_in[0];
    const float* W_in  = (const float*)d_in[1];
    const float* b_in  = (const float*)d_in[2];
    const float* W_f   = (const float*)d_in[3];
    const float* b_f   = (const float*)d_in[4];
    const float* W_g   = (const float*)d_in[5];
    const float* b_g   = (const float*)d_in[6];
    const float* W_s   = (const float*)d_in[7];
    const float* b_s   = (const float*)d_in[8];
    const float* W_o   = (const float*)d_in[9];
    const float* b_o   = (const float*)d_in[10];
    const float* W_sk1 = (const float*)d_in[11];
    const float* b_sk1 = (const float*)d_in[12];
    const float* W_sk2 = (const float*)d_in[13];
    const float* b_sk2 = (const float*)d_in[14];
    float* outp = (float*)d_out;

    float* streams = (float*)d_ws;                 // 15*BT floats (30 MB)
    float* fw      = streams + (size_t)15 * BT;    // FW_F32 floats
    short* fwh     = (short*)(fw + FW_F32);        // bf16 tables

    int prep_items = 576 + WSBF_N + W1BF_N;
    prep_kernel<<<(prep_items + 255) / 256, 256, 0, stream>>>(
        W_f, W_g, W_in, b_in, b_f, b_g, b_s, W_s, W_sk1, fw, fwh);
    for (int i = 0; i < 15; ++i) {
        int d = 1 << (i & 7);
        const float* src = (i == 0) ? x : streams + (size_t)(i - 1) * BT;
        layer_kernel<<<B_N * (T_LEN / CL), NT1, 0, stream>>>(
            src, streams + (size_t)i * BT, fw + i * FW_L, W_o + i * 32, b_o + i, d);
    }
    pass2_kernel<<<B_N * (T_LEN / TS), 256, 0, stream>>>(
        x, streams, fw, fwh, fwh + WSBF_N, b_sk1, W_sk2, b_sk2, outp);
}